// Round 10
// baseline (406.917 us; speedup 1.0000x reference)
//
#include <hip/hip_runtime.h>
#include <hip/hip_bf16.h>

typedef float f32x4 __attribute__((ext_vector_type(4)));
typedef short s16x8 __attribute__((ext_vector_type(8)));
typedef unsigned short u16;

#define NH 12
#define DH 64
#define DM 768
#define S_LEN 2048
#define B_SZ 4

static __device__ __forceinline__ u16 f2bf(float f) {
  __hip_bfloat16 h = __float2bfloat16(f);
  return __builtin_bit_cast(u16, h);
}
// load 8 consecutive f32 from global, return packed bf16 x8
static __device__ __forceinline__ s16x8 ld8_f32_to_bf16(const float* p) {
  float4 a = *(const float4*)p;
  float4 b = *(const float4*)(p + 4);
  s16x8 r;
  r[0] = (short)f2bf(a.x); r[1] = (short)f2bf(a.y);
  r[2] = (short)f2bf(a.z); r[3] = (short)f2bf(a.w);
  r[4] = (short)f2bf(b.x); r[5] = (short)f2bf(b.y);
  r[6] = (short)f2bf(b.z); r[7] = (short)f2bf(b.w);
  return r;
}

// ---------------------------------------------------------------------------
// RoPE cos/sin table: tab[pos*32+i] = {cos,sin}(pos * 10000^(-2i/64)).
// Precise sincosf (angles reach 2047 rad; native v_sin invalid out there).
// ---------------------------------------------------------------------------
__global__ __launch_bounds__(256) void rope_table_kernel(float2* __restrict__ tab) {
  const int idx = blockIdx.x * 256 + threadIdx.x;   // 0..65535 exact
  const int sl = idx >> 5, i = idx & 31;
  const float inv_freq = exp2f((float)(2 * i) * (-13.287712379549449f / 64.0f));
  float s, c;
  sincosf((float)sl * inv_freq, &s, &c);
  tab[idx] = make_float2(c, s);
}

// ---------------------------------------------------------------------------
// QKV projection + RoPE (r9-validated). f32 in -> bf16 staging.
// q: (b,h,s,d) pre-scaled by 0.125*log2e; k: (b,h,s,d); v: (b,h,d,s) transposed.
// ---------------------------------------------------------------------------
#define AST 40
#define QSCALE 0.18033688011112042f   // 0.125 * log2(e)

__global__ __launch_bounds__(256) void qkv_rope_kernel(
    const float* __restrict__ x, const float* __restrict__ wq,
    const float* __restrict__ wk, const float* __restrict__ wv,
    const float2* __restrict__ tab,
    u16* __restrict__ qo, u16* __restrict__ ko, u16* __restrict__ vo)
{
  const int z = blockIdx.z;                 // 0=q 1=k 2=v
  const float* Wp = (z == 0) ? wq : (z == 1) ? wk : wv;
  u16* Op = (z == 0) ? qo : (z == 1) ? ko : vo;
  const int mTile = blockIdx.x * 64;
  const int nTile = blockIdx.y * 64;
  const int tid = threadIdx.x;
  const int wave = tid >> 6, lane = tid & 63;
  const int lm = lane & 15, lq = lane >> 4;

  __shared__ u16 Al[64 * AST];
  __shared__ u16 Wl[64 * AST];

  f32x4 acc[4];
#pragma unroll
  for (int i = 0; i < 4; ++i) acc[i] = (f32x4){0.f, 0.f, 0.f, 0.f};

  const int srow = tid >> 2, scol = (tid & 3) * 8;   // 64 rows x 32 cols

  for (int k0 = 0; k0 < DM; k0 += 32) {
    __syncthreads();
    *(s16x8*)&Al[srow * AST + scol] =
        ld8_f32_to_bf16(&x[(size_t)(mTile + srow) * DM + k0 + scol]);
    *(s16x8*)&Wl[srow * AST + scol] =
        ld8_f32_to_bf16(&Wp[(size_t)(nTile + srow) * DM + k0 + scol]);
    __syncthreads();
    s16x8 af = *(const s16x8*)&Al[(wave * 16 + lm) * AST + lq * 8];
#pragma unroll
    for (int nt = 0; nt < 4; ++nt) {
      s16x8 bf = *(const s16x8*)&Wl[(nt * 16 + lm) * AST + lq * 8];
      acc[nt] = __builtin_amdgcn_mfma_f32_16x16x32_bf16(af, bf, acc[nt], 0, 0, 0);
    }
  }

  // C/D layout (m89): col = lane&15, row = (lane>>4)*4 + r; RoPE partner in lane^1
#pragma unroll
  for (int nt = 0; nt < 4; ++nt) {
#pragma unroll
    for (int r = 0; r < 4; ++r) {
      float val = acc[nt][r];
      float partner = __shfl_xor(val, 1);
      const int mI = mTile + wave * 16 + lq * 4 + r;   // token 0..8191
      const int nI = nTile + nt * 16 + lm;             // feature 0..767
      const int b = mI >> 11, sl2 = mI & (S_LEN - 1);
      const int h = nI >> 6, dd = nI & 63;
      float res;
      if (z < 2) {
        const float2 cs = tab[sl2 * 32 + (dd >> 1)];
        res = val * cs.x + partner * ((dd & 1) ? cs.y : -cs.y);
        if (z == 0) res *= QSCALE;
        Op[(((size_t)(b * NH + h)) * S_LEN + sl2) * DH + dd] = f2bf(res);
      } else {
        Op[(((size_t)(b * NH + h)) * DH + dd) * S_LEN + sl2] = f2bf(val);
      }
    }
  }
}

// ---------------------------------------------------------------------------
// MFMA flash attention, TRIANGULAR-PAIRED for load balance. Block = 4 waves,
// handles TWO 64-query tiles of one (b,h): JA = 31-i (heavy), JB = i (light).
// JB's key range is a prefix of JA's => one K/V staging serves both, and
// per-block m-group visits are CONSTANT (33 per wave) across the grid
// (r9's 1..32x triangular imbalance was the 85%-idle cause). kf/vf fragments
// are loaded once and MFMA'd into both tiles' accumulators. Online softmax
// in exp2 units. Output bf16 to aw (b,s,dm).
// ---------------------------------------------------------------------------
#define KVST 72

__global__ __launch_bounds__(256) void attn_kernel(
    const u16* __restrict__ q, const u16* __restrict__ k,
    const u16* __restrict__ vt, u16* __restrict__ o)
{
  const int i = blockIdx.x;                 // pair index 0..15
  const int bh = blockIdx.y;
  const int JA = 31 - i, JB = i;            // 64-query tile indices
  const size_t base = (size_t)bh * S_LEN * DH;
  const int tid = threadIdx.x;
  const int wave = tid >> 6, lane = tid & 63;
  const int lm = lane & 15, lq = lane >> 4;

  __shared__ u16 Kl[64 * KVST];             // [key][d]
  __shared__ u16 Vl[64 * KVST];             // [d][key]
  __shared__ u16 Pl[4 * 32 * KVST];         // per-wave: 16 rows JA + 16 rows JB

  const int qmA = JA * 64 + wave * 16;
  const int qmB = JB * 64 + wave * 16;

  s16x8 aqA[2], aqB[2];
#pragma unroll
  for (int kk = 0; kk < 2; ++kk) {
    aqA[kk] = *(const s16x8*)&q[base + (size_t)(qmA + lm) * DH + kk * 32 + lq * 8];
    aqB[kk] = *(const s16x8*)&q[base + (size_t)(qmB + lm) * DH + kk * 32 + lq * 8];
  }

  f32x4 OA[4], OB[4];
  float mA[4], lA[4], mB[4], lB[4];
#pragma unroll
  for (int r = 0; r < 4; ++r) {
    OA[r] = (f32x4){0.f, 0.f, 0.f, 0.f};
    OB[r] = (f32x4){0.f, 0.f, 0.f, 0.f};
    mA[r] = -1e30f; lA[r] = 0.f;
    mB[r] = -1e30f; lB[r] = 0.f;
  }

  const int srow = tid >> 2, scol16 = (tid & 3) * 16;

  for (int t = 0; t <= JA; ++t) {
    __syncthreads();                        // prev tile's Kl/Vl/Pl reads done
    {
      const uint4* kg = (const uint4*)
          &k[base + (size_t)(t * 64 + srow) * DH + scol16];
      uint4 a0 = kg[0], a1 = kg[1];
      *(uint4*)&Kl[srow * KVST + scol16] = a0;
      *(uint4*)&Kl[srow * KVST + scol16 + 8] = a1;
      const uint4* vg = (const uint4*)
          &vt[base + (size_t)srow * S_LEN + t * 64 + scol16];
      uint4 b0 = vg[0], b1 = vg[1];
      *(uint4*)&Vl[srow * KVST + scol16] = b0;
      *(uint4*)&Vl[srow * KVST + scol16 + 8] = b1;
    }
    __syncthreads();

    const bool actB = (t <= JB);            // block-uniform

    // S = Q K^T — kf loaded once, used for both q-tiles
    f32x4 SA[4], SB[4];
#pragma unroll
    for (int n = 0; n < 4; ++n) {
      SA[n] = (f32x4){0.f, 0.f, 0.f, 0.f};
      SB[n] = (f32x4){0.f, 0.f, 0.f, 0.f};
    }
#pragma unroll
    for (int kk = 0; kk < 2; ++kk) {
#pragma unroll
      for (int nt = 0; nt < 4; ++nt) {
        s16x8 kf = *(const s16x8*)&Kl[(nt * 16 + lm) * KVST + kk * 32 + lq * 8];
        SA[nt] = __builtin_amdgcn_mfma_f32_16x16x32_bf16(aqA[kk], kf, SA[nt], 0, 0, 0);
        if (actB)
          SB[nt] = __builtin_amdgcn_mfma_f32_16x16x32_bf16(aqB[kk], kf, SB[nt], 0, 0, 0);
      }
    }

    if (t == JA) {                          // diagonal of heavy tile
#pragma unroll
      for (int nt = 0; nt < 4; ++nt)
#pragma unroll
        for (int r = 0; r < 4; ++r)
          if (t * 64 + nt * 16 + lm > qmA + lq * 4 + r) SA[nt][r] = -1e30f;
    }
    if (actB && t == JB) {                  // diagonal of light tile
#pragma unroll
      for (int nt = 0; nt < 4; ++nt)
#pragma unroll
        for (int r = 0; r < 4; ++r)
          if (t * 64 + nt * 16 + lm > qmB + lq * 4 + r) SB[nt][r] = -1e30f;
    }

    // online softmax (exp2 units); row = 16 lanes sharing lq
#pragma unroll
    for (int r = 0; r < 4; ++r) {
      {
        float rm = fmaxf(fmaxf(SA[0][r], SA[1][r]), fmaxf(SA[2][r], SA[3][r]));
        rm = fmaxf(rm, __shfl_xor(rm, 1));
        rm = fmaxf(rm, __shfl_xor(rm, 2));
        rm = fmaxf(rm, __shfl_xor(rm, 4));
        rm = fmaxf(rm, __shfl_xor(rm, 8));
        const float mn = fmaxf(mA[r], rm);
        const float alpha = exp2f(mA[r] - mn);
        float rs = 0.f;
#pragma unroll
        for (int nt = 0; nt < 4; ++nt) {
          float p = exp2f(SA[nt][r] - mn);
          SA[nt][r] = p; rs += p;
        }
        rs += __shfl_xor(rs, 1); rs += __shfl_xor(rs, 2);
        rs += __shfl_xor(rs, 4); rs += __shfl_xor(rs, 8);
        lA[r] = lA[r] * alpha + rs; mA[r] = mn;
#pragma unroll
        for (int nt = 0; nt < 4; ++nt) OA[nt][r] *= alpha;
      }
      if (actB) {
        float rm = fmaxf(fmaxf(SB[0][r], SB[1][r]), fmaxf(SB[2][r], SB[3][r]));
        rm = fmaxf(rm, __shfl_xor(rm, 1));
        rm = fmaxf(rm, __shfl_xor(rm, 2));
        rm = fmaxf(rm, __shfl_xor(rm, 4));
        rm = fmaxf(rm, __shfl_xor(rm, 8));
        const float mn = fmaxf(mB[r], rm);
        const float alpha = exp2f(mB[r] - mn);
        float rs = 0.f;
#pragma unroll
        for (int nt = 0; nt < 4; ++nt) {
          float p = exp2f(SB[nt][r] - mn);
          SB[nt][r] = p; rs += p;
        }
        rs += __shfl_xor(rs, 1); rs += __shfl_xor(rs, 2);
        rs += __shfl_xor(rs, 4); rs += __shfl_xor(rs, 8);
        lB[r] = lB[r] * alpha + rs; mB[r] = mn;
#pragma unroll
        for (int nt = 0; nt < 4; ++nt) OB[nt][r] *= alpha;
      }
    }

    // P: C-layout regs -> per-wave LDS -> A-layout (same-wave: no barrier)
#pragma unroll
    for (int nt = 0; nt < 4; ++nt)
#pragma unroll
      for (int r = 0; r < 4; ++r) {
        Pl[(wave * 32 + lq * 4 + r) * KVST + nt * 16 + lm] = f2bf(SA[nt][r]);
        if (actB)
          Pl[(wave * 32 + 16 + lq * 4 + r) * KVST + nt * 16 + lm] = f2bf(SB[nt][r]);
      }

    // O += P V — vf loaded once, used for both q-tiles
#pragma unroll
    for (int kk = 0; kk < 2; ++kk) {
      s16x8 paA = *(const s16x8*)&Pl[(wave * 32 + lm) * KVST + kk * 32 + lq * 8];
      s16x8 paB = *(const s16x8*)&Pl[(wave * 32 + 16 + lm) * KVST + kk * 32 + lq * 8];
#pragma unroll
      for (int nt = 0; nt < 4; ++nt) {
        s16x8 vf = *(const s16x8*)&Vl[(nt * 16 + lm) * KVST + kk * 32 + lq * 8];
        OA[nt] = __builtin_amdgcn_mfma_f32_16x16x32_bf16(paA, vf, OA[nt], 0, 0, 0);
        if (actB)
          OB[nt] = __builtin_amdgcn_mfma_f32_16x16x32_bf16(paB, vf, OB[nt], 0, 0, 0);
      }
    }
  }

  // normalize + store bf16 to aw (b, s, h*64+d)
  const int b = bh / NH, h = bh % NH;
#pragma unroll
  for (int nt = 0; nt < 4; ++nt)
#pragma unroll
    for (int r = 0; r < 4; ++r) {
      const int dd = nt * 16 + lm;
      o[((size_t)(b * S_LEN + qmA + lq * 4 + r)) * DM + h * DH + dd] =
          f2bf(OA[nt][r] / lA[r]);
      o[((size_t)(b * S_LEN + qmB + lq * 4 + r)) * DM + h * DH + dd] =
          f2bf(OB[nt][r] / lB[r]);
    }
}

// ---------------------------------------------------------------------------
// Out-projection GEMM (r8-validated): C = aw @ wo^T. A bf16, B f32->bf16 at
// staging, C f32 to d_out. 64x64 tile, BK=32, 1536 blocks.
// ---------------------------------------------------------------------------
__global__ __launch_bounds__(256) void out_proj_kernel(
    const u16* __restrict__ a, const float* __restrict__ wo,
    float* __restrict__ c)
{
  const int mTile = blockIdx.x * 64;
  const int nTile = blockIdx.y * 64;
  const int tid = threadIdx.x;
  const int wave = tid >> 6, lane = tid & 63;
  const int lm = lane & 15, lq = lane >> 4;

  __shared__ u16 Al[64 * AST];
  __shared__ u16 Wl[64 * AST];

  f32x4 acc[4];
#pragma unroll
  for (int i = 0; i < 4; ++i) acc[i] = (f32x4){0.f, 0.f, 0.f, 0.f};

  const int srow = tid >> 2, scol = (tid & 3) * 8;

  for (int k0 = 0; k0 < DM; k0 += 32) {
    __syncthreads();
    *(uint4*)&Al[srow * AST + scol] =
        *(const uint4*)&a[(size_t)(mTile + srow) * DM + k0 + scol];
    *(s16x8*)&Wl[srow * AST + scol] =
        ld8_f32_to_bf16(&wo[(size_t)(nTile + srow) * DM + k0 + scol]);
    __syncthreads();
    s16x8 af = *(const s16x8*)&Al[(wave * 16 + lm) * AST + lq * 8];
#pragma unroll
    for (int nt = 0; nt < 4; ++nt) {
      s16x8 bf = *(const s16x8*)&Wl[(nt * 16 + lm) * AST + lq * 8];
      acc[nt] = __builtin_amdgcn_mfma_f32_16x16x32_bf16(af, bf, acc[nt], 0, 0, 0);
    }
  }

#pragma unroll
  for (int nt = 0; nt < 4; ++nt)
#pragma unroll
    for (int r = 0; r < 4; ++r)
      c[(size_t)(mTile + wave * 16 + lq * 4 + r) * DM + nTile + nt * 16 + lm] =
          acc[nt][r];
}

// ---------------------------------------------------------------------------
extern "C" void kernel_launch(void* const* d_in, const int* in_sizes, int n_in,
                              void* d_out, int out_size, void* d_ws, size_t ws_size,
                              hipStream_t stream) {
  const float* x  = (const float*)d_in[0];   // inputs: float32 (r4-confirmed)
  const float* wq = (const float*)d_in[1];
  const float* wk = (const float*)d_in[2];
  const float* wv = (const float*)d_in[3];
  const float* wo = (const float*)d_in[4];
  float* out = (float*)d_out;                // output: float32 (r6-confirmed)
  u16* ws  = (u16*)d_ws;

  const size_t QKV = (size_t)B_SZ * S_LEN * DM;  // 6291456 elems
  u16* qw = ws;                                  // ws: 4*QKV*2 + 512KB = 50.9MB
  u16* kw = ws + QKV;
  u16* vw = ws + 2 * QKV;                        // v TRANSPOSED (b,h,d,s)
  u16* aw = ws + 3 * QKV;                        // attention out, bf16 (b,s,dm)
  float2* tab = (float2*)(ws + 4 * QKV);         // 2048 x 32 cos/sin

  rope_table_kernel<<<dim3(S_LEN * 32 / 256), 256, 0, stream>>>(tab);
  qkv_rope_kernel<<<dim3(128, 12, 3), 256, 0, stream>>>(
      x, wq, wk, wv, tab, qw, kw, vw);
  attn_kernel<<<dim3(16, B_SZ * NH), 256, 0, stream>>>(qw, kw, vw, aw);
  out_proj_kernel<<<dim3(128, 12), 256, 0, stream>>>(aw, wo, out);
}